// Round 3
// baseline (81.886 us; speedup 1.0000x reference)
//
#include <hip/hip_runtime.h>
#include <hip/hip_bf16.h>

// TT-embedding: VOC = 100*100*100, EMB = 4*4*8, RANK = 16, PAD_IDX = 0.
// core0 [1,100,4,16] (A), core1 [16,100,4,16] (B), core2 [16,100,8,1] (C), float32.
// x [64,512] int indices; out [64,512,128] float32.
//
// emb[j1,j2,j3] = sum_{r1,r2} A(i1)[j1,r1] * B(i2)[r1,j2,r2] * C(i3)[r2,j3]
// Contraction order (min MACs): T[j1,j2,r2] = sum_r1 A*B   (4096 MAC/token)
//                               emb         = sum_r2 T*C   (2048 MAC/token)
// 6144 MAC/token vs 10240 for the (B*C)-first order.

// Per-wave LDS floats: At[64] | Cs[128] | Bs[1024] | Ts[16*17=272]  = 1488
#define AT_OFF 0
#define CS_OFF 64
#define BS_OFF 192
#define TS_OFF 1216
#define LDS_PER_WAVE 1488   // 5952 B; x4 waves = 23808 B/block

__global__ __launch_bounds__(256) void tt_embed_kernel(
    const int* __restrict__ x,
    const float* __restrict__ c0,   // [100,4,16]   A[i1][j1][r1]
    const float* __restrict__ c1,   // [16,100,4,16] B[r1][i2][j2][r2]
    const float* __restrict__ c2,   // [16,100,8]   C[r2][i3][j3]
    float* __restrict__ out,        // [nTok,128]
    int nTok)
{
    __shared__ float lds[4 * LDS_PER_WAVE];
    const int wave = threadIdx.x >> 6;
    const int lane = threadIdx.x & 63;
    const int t = blockIdx.x * 4 + wave;
    const bool active = (t < nTok);

    float* At = lds + wave * LDS_PER_WAVE + AT_OFF;   // At[r1*4 + j1]
    float* Cs = lds + wave * LDS_PER_WAVE + CS_OFF;   // Cs[r2*8 + j3]
    float* Bs = lds + wave * LDS_PER_WAVE + BS_OFF;   // Bs[r1*64 + j2*16 + r2]
    float* Ts = lds + wave * LDS_PER_WAVE + TS_OFF;   // Ts[(j1*4+j2)*17 + r2]

    int idx = 0;
    if (active) idx = x[t];
    const int i1 = idx / 10000;
    const int rem = idx - i1 * 10000;
    const int i2 = rem / 100;
    const int i3 = rem - i2 * 100;

    if (active) {
        // ---- Stage A (transposed): At[r1*4+j1] = A[i1][j1][r1]; 64 lanes x 1 float
        {
            const int j1 = lane >> 4;
            const int r1 = lane & 15;
            At[r1 * 4 + j1] = c0[i1 * 64 + j1 * 16 + r1];   // coalesced 256B segment
        }
        // ---- Stage C: Cs[r2*8 + j3] = C[r2][i3][j3]; 32 lanes x float4
        if (lane < 32) {
            const int r2 = lane >> 1;
            const int half = lane & 1;
            ((float4*)Cs)[lane] = *(const float4*)(c2 + (r2 * 100 + i3) * 8 + half * 4);
        }
        // ---- Stage B: Bs same layout as global slice; 64 lanes x 4 float4
        #pragma unroll
        for (int k = 0; k < 4; ++k) {
            const int f = k * 64 + lane;          // float4 index in 1024-float slice
            const int r1 = f >> 4;
            const int w = f & 15;
            ((float4*)Bs)[f] = *((const float4*)(c1 + (r1 * 100 + i2) * 64) + w);
        }
    }

    __syncthreads();   // At/Cs/Bs visible

    // ---- Stage 1: lane = (j2, r2): T[j1=0..3, j2, r2] = sum_r1 A[j1,r1]*B[r1,j2,r2]
    const int j2 = lane & 3;
    const int r2s = lane >> 2;
    float tac[4] = {0.f, 0.f, 0.f, 0.f};
    #pragma unroll
    for (int r1 = 0; r1 < 16; ++r1) {
        const float4 a4 = *(const float4*)(At + r1 * 4);          // wave-uniform -> broadcast
        const float b = Bs[r1 * 64 + j2 * 16 + r2s];              // 2-way bank alias: free
        tac[0] += a4.x * b;
        tac[1] += a4.y * b;
        tac[2] += a4.z * b;
        tac[3] += a4.w * b;
    }
    #pragma unroll
    for (int j1 = 0; j1 < 4; ++j1) {
        Ts[(j1 * 4 + j2) * 17 + r2s] = tac[j1];                   // pad 17 -> ~2-way max
    }

    __syncthreads();   // Ts visible

    // ---- Stage 2: lane produces out elems e0=2*lane, e0+1; q=j1*4+j2, j3=e0&7
    const int q = lane >> 2;
    const int j3 = (2 * lane) & 7;
    float o0 = 0.f, o1 = 0.f;
    #pragma unroll
    for (int r2 = 0; r2 < 16; ++r2) {
        const float tv = Ts[q * 17 + r2];                         // 16 banks, 4-lane bcast
        const float2 cv = *(const float2*)(Cs + r2 * 8 + j3);     // 4 addrs, bcast
        o0 += tv * cv.x;
        o1 += tv * cv.y;
    }

    if (idx == 0) { o0 = 0.f; o1 = 0.f; }   // PAD_IDX -> zero row

    if (active) {
        *(float2*)(out + (long)t * 128 + 2 * lane) = make_float2(o0, o1);
    }
}

extern "C" void kernel_launch(void* const* d_in, const int* in_sizes, int n_in,
                              void* d_out, int out_size, void* d_ws, size_t ws_size,
                              hipStream_t stream) {
    const int*   x  = (const int*)d_in[0];
    const float* c0 = (const float*)d_in[1];
    const float* c1 = (const float*)d_in[2];
    const float* c2 = (const float*)d_in[3];
    float* out = (float*)d_out;

    const int nTok = out_size / 128;           // 64*512 = 32768
    const int blocks = (nTok + 3) / 4;         // one wave per token
    tt_embed_kernel<<<dim3(blocks), dim3(256), 0, stream>>>(x, c0, c1, c2, out, nTok);
}